// Round 4
// baseline (65.998 us; speedup 1.0000x reference)
//
#include <hip/hip_runtime.h>

// Problem: left/right [2,32,64,128] f32, MAXDISP=192 (D=48 coarse) -> out [2,256,512]
#define BB 2
#define CC 32
#define HC 64
#define WC 128
#define HO 256
#define WO 512
#define MAXD 192
#define NBLK2 1024            // 2 blocks per output row (half-row x dd-half split)
#define RPAD 47               // zero pad in front of Rh
#define RSZ  176              // 47 zeros + 128 values + 1 zero guard (w0=127, d=0)

// One dd-quarter: dd in [48K, 48K+47]. Coarse segment d = dd*47/191. Per segment,
// vv[j] (d = DLO+j) = base(d) + c0*Rh[w0-d] + c1*Rh[w1-d]  (R masks via zero pad,
// L mask via saturate on masked waves). All coefficients pre-scaled by log2(e)/64.
// Within a segment the softmax argument is LINEAR in dd (step s*KD): geometric
// chain e *= exp2(s*KD) -> 2 v_exp_f32 per segment. Parity-split accumulators.
#define QUARTER(K, MASKED)                                                     \
  {                                                                            \
    constexpr int DDLO = 48 * (K);                                             \
    constexpr int DDHI = DDLO + 47;                                            \
    constexpr int DLO  = (DDLO * 47) / 191;                                    \
    constexpr int DHI  = (DDHI * 47) / 191;                                    \
    constexpr int NV   = DHI - DLO + 2;                                        \
    float vv[NV];                                                              \
    _Pragma("unroll")                                                          \
    for (int j = 0; j < NV; ++j) {                                             \
      int d = DLO + j;                                                         \
      if (d > 47) {                                                            \
        vv[j] = vv[j - 1];              /* v[48] := v[47] (wd=0 there) */      \
      } else {                                                                 \
        float t0 = Rhp[RPAD + w0 - d];        /* Rh[w0-d], 0 if w0<d  */       \
        float t1 = Rhp[RPAD + w0 - d + 1];    /* Rh[w1-d], 0 if w1<d  */       \
        float bn;                                                              \
        if (MASKED) {                                                          \
          float df = (float)d;                                                 \
          bn = fmaf(cB0, __saturatef(w0f - df + 1.f),                          \
                    cB1 * __saturatef(w0f - df + 2.f));                        \
        } else {                                                               \
          bn = cA;                                                             \
        }                                                                      \
        vv[j] = fmaf(c0, t0, fmaf(c1, t1, bn));                                \
      }                                                                        \
    }                                                                          \
    _Pragma("unroll")                                                          \
    for (int j = DLO; j <= DHI; ++j) {                                         \
      int dd0 = (191 * j + 46) / 47;  if (dd0 < DDLO) dd0 = DDLO;              \
      int dd1 = (191 * j + 190) / 47; if (dd1 > DDHI) dd1 = DDHI;              \
      float s   = vv[j - DLO + 1] - vv[j - DLO];                               \
      float wd0 = (float)dd0 * (47.0f / 191.0f) - (float)j;                    \
      float e   = __builtin_amdgcn_exp2f(fmaf(wd0, s, vv[j - DLO]));           \
      float rr  = 1.f;                                                         \
      if (dd1 > dd0) rr = __builtin_amdgcn_exp2f(s * (47.0f / 191.0f));        \
      _Pragma("unroll")                                                        \
      for (int dd = dd0; dd <= dd1; ++dd) {                                    \
        if (dd & 1) { ls1 += e; ss1 = fmaf(e, (float)dd, ss1); }               \
        else        { ls0 += e; ss0 = fmaf(e, (float)dd, ss0); }               \
        if (dd < dd1) e *= rr;                                                 \
      }                                                                        \
    }                                                                          \
  }

__global__ __launch_bounds__(512)
__attribute__((amdgpu_waves_per_eu(8, 8)))   // 64-VGPR budget -> 8 waves/SIMD
void fused_disp_kernel(const float* __restrict__ left,
                       const float* __restrict__ right,
                       float* __restrict__ out) {
    __shared__ float4 red[2][8][32];   // [mat][channel-group][w-quad]
    __shared__ float  Lh[WC];
    __shared__ float  Rhp[RSZ];
    __shared__ float  redL[2][256];    // [dd-half][pixel]
    __shared__ float  redS[2][256];

    // XCD-contiguous bijective swizzle (1024 % 8 == 0): 128 consecutive
    // (row,half) units per XCD -> input slab stays L2-resident.
    int blk = blockIdx.x;
    int u   = (blk & 7) * (NBLK2 / 8) + (blk >> 3);
    int r   = u >> 1;                  // output row [0, 512)
    int g   = u & 1;                   // column half
    int b   = r >> 8;
    int hh  = r & (HO - 1);

    float src_h = (float)hh * (63.0f / 255.0f);
    int h0 = (int)src_h; if (h0 > HC - 1) h0 = HC - 1;
    int h1 = h0 + 1;     if (h1 > HC - 1) h1 = HC - 1;
    float fh = src_h - (float)h0;

    int t = threadIdx.x;

    // ---- Phase 0: fused channel-sum (32 ch) + fh row blend, float4 loads ----
    {
        int mat = t >> 8;          // 0=left 1=right
        int uu  = t & 255;
        int cg  = uu >> 5;         // 8 groups of 4 channels
        int wq  = uu & 31;         // float4 quad in w
        const float* srcp = (mat ? right : left) + (size_t)b * (CC * HC * WC);
        float ax = 0.f, ay = 0.f, az = 0.f, aw = 0.f;
        float bx = 0.f, by = 0.f, bz = 0.f, bw = 0.f;
#pragma unroll
        for (int i = 0; i < 4; ++i) {
            int c = cg * 4 + i;
            float4 v0 = *(const float4*)(srcp + ((c * HC + h0) * WC + wq * 4));
            float4 v1 = *(const float4*)(srcp + ((c * HC + h1) * WC + wq * 4));
            ax += v0.x; ay += v0.y; az += v0.z; aw += v0.w;
            bx += v1.x; by += v1.y; bz += v1.z; bw += v1.w;
        }
        float gh = 1.f - fh;
        red[mat][cg][wq] = make_float4(fmaf(gh, ax, fh * bx), fmaf(gh, ay, fh * by),
                                       fmaf(gh, az, fh * bz), fmaf(gh, aw, fh * bw));
    }
    __syncthreads();
    // reduce the 8 channel-groups -> Lh[128] / Rhp[47..174]; zero the pads
    if (t < 256) {
        int mat = t >> 7;
        int w   = t & 127;
        const float* redf = (const float*)red;
        float s = 0.f;
#pragma unroll
        for (int cgi = 0; cgi < 8; ++cgi) s += redf[(mat * 8 + cgi) * 128 + w];
        if (mat == 0) Lh[w] = s;
        else          Rhp[RPAD + w] = s;
    } else {
        int z = t - 256;
        if (z < RPAD)       Rhp[z] = 0.f;        // leading zeros (R mask)
        else if (z == RPAD) Rhp[RSZ - 1] = 0.f;  // guard for w0==127, d==0
    }
    __syncthreads();

    // ---- Phase 2: 256 pixels x 2 dd-halves; 2 quarters per thread ----
    int p  = t & 255;                  // pixel within half-row
    int k  = t >> 8;                   // dd half: 0 -> dd[0,95], 1 -> dd[96,191]
    int ww = g * 256 + p;

    float src_w = (float)ww * (127.0f / 511.0f);
    int w0 = (int)src_w; if (w0 > WC - 1) w0 = WC - 1;
    int w1 = w0 + 1;     if (w1 > WC - 1) w1 = WC - 1;
    float fw = src_w - (float)w0;

    const float L2E_SC = 1.4426950408889634f / 64.0f;  // log2(e) * (1/64 mean)
    float c0  = (1.f - fw) * L2E_SC;
    float c1  = fw * L2E_SC;
    float lw0 = Lh[w0], lw1 = Lh[w1];
    float cB0 = c0 * lw0, cB1 = c1 * lw1;
    float cA  = cB0 + cB1;
    float w0f = (float)w0;

    float ls0 = 0.f, ls1 = 0.f, ss0 = 0.f, ss1 = 0.f;
    // masked base needed only when w0 < 47, i.e. g==0 && p < 192 (wave-uniform).
    if (k == 0) {
        if (g == 0 && p < 192) { QUARTER(0, true)  QUARTER(1, true)  }
        else                   { QUARTER(0, false) QUARTER(1, false) }
    } else {
        if (g == 0 && p < 192) { QUARTER(2, true)  QUARTER(3, true)  }
        else                   { QUARTER(2, false) QUARTER(3, false) }
    }
    redL[k][p] = ls0 + ls1;
    redS[k][p] = ss0 + ss1;
    __syncthreads();

    // ---- Phase 3: combine dd-halves, soft-argmin, coalesced store ----
    if (t < 256) {
        float ls = redL[0][t] + redL[1][t];
        float ss = redS[0][t] + redS[1][t];
        out[(size_t)r * WO + g * 256 + t] = ss / ls;
    }
}

extern "C" void kernel_launch(void* const* d_in, const int* in_sizes, int n_in,
                              void* d_out, int out_size, void* d_ws, size_t ws_size,
                              hipStream_t stream) {
    const float* left  = (const float*)d_in[0];
    const float* right = (const float*)d_in[1];
    fused_disp_kernel<<<NBLK2, 512, 0, stream>>>(left, right, (float*)d_out);
}

// Round 5
// 64.308 us; speedup vs baseline: 1.0263x; 1.0263x over previous
//
#include <hip/hip_runtime.h>

// Problem: left/right [2,32,64,128] f32, MAXDISP=192 (D=48 coarse) -> out [2,256,512]
#define BB 2
#define CC 32
#define HC 64
#define WC 128
#define HO 256
#define WO 512
#define MAXD 192
#define NBLK (BB * HO)        // 512 blocks, one per output row (phase-0 work as in R3)
#define RPAD 47               // zero pad in front of Rh
#define RSZ  176              // 47 zeros + 128 values + 1 zero guard (w0=127, d=0)

// One dd-quarter: dd in [48K, 48K+47]. Coarse segment d = dd*47/191. Per segment,
// vv[j] (d = DLO+j) = base(d) + c0*Rh[w0-d] + c1*Rh[w1-d]  (R masks via zero pad,
// L mask via saturate on masked waves). All coefficients pre-scaled by log2(e)/64.
// Within a segment the softmax argument is LINEAR in dd (step s*KD): geometric
// chain e *= exp2(s*KD) -> 2 v_exp_f32 per segment. Parity-split accumulators.
#define QUARTER(K, MASKED)                                                     \
  {                                                                            \
    constexpr int DDLO = 48 * (K);                                             \
    constexpr int DDHI = DDLO + 47;                                            \
    constexpr int DLO  = (DDLO * 47) / 191;                                    \
    constexpr int DHI  = (DDHI * 47) / 191;                                    \
    constexpr int NV   = DHI - DLO + 2;                                        \
    float vv[NV];                                                              \
    _Pragma("unroll")                                                          \
    for (int j = 0; j < NV; ++j) {                                             \
      int d = DLO + j;                                                         \
      if (d > 47) {                                                            \
        vv[j] = vv[j - 1];              /* v[48] := v[47] (wd=0 there) */      \
      } else {                                                                 \
        float t0 = Rhp[RPAD + w0 - d];        /* Rh[w0-d], 0 if w0<d  */       \
        float t1 = Rhp[RPAD + w0 - d + 1];    /* Rh[w1-d], 0 if w1<d  */       \
        float bn;                                                              \
        if (MASKED) {                                                          \
          float df = (float)d;                                                 \
          bn = fmaf(cB0, __saturatef(w0f - df + 1.f),                          \
                    cB1 * __saturatef(w0f - df + 2.f));                        \
        } else {                                                               \
          bn = cA;                                                             \
        }                                                                      \
        vv[j] = fmaf(c0, t0, fmaf(c1, t1, bn));                                \
      }                                                                        \
    }                                                                          \
    _Pragma("unroll")                                                          \
    for (int j = DLO; j <= DHI; ++j) {                                         \
      int dd0 = (191 * j + 46) / 47;  if (dd0 < DDLO) dd0 = DDLO;              \
      int dd1 = (191 * j + 190) / 47; if (dd1 > DDHI) dd1 = DDHI;              \
      float s   = vv[j - DLO + 1] - vv[j - DLO];                               \
      float wd0 = (float)dd0 * (47.0f / 191.0f) - (float)j;                    \
      float e   = __builtin_amdgcn_exp2f(fmaf(wd0, s, vv[j - DLO]));           \
      float rr  = 1.f;                                                         \
      if (dd1 > dd0) rr = __builtin_amdgcn_exp2f(s * (47.0f / 191.0f));        \
      _Pragma("unroll")                                                        \
      for (int dd = dd0; dd <= dd1; ++dd) {                                    \
        if (dd & 1) { ls1 += e; ss1 = fmaf(e, (float)dd, ss1); }               \
        else        { ls0 += e; ss0 = fmaf(e, (float)dd, ss0); }               \
        if (dd < dd1) e *= rr;                                                 \
      }                                                                        \
    }                                                                          \
  }

__global__ __launch_bounds__(1024)
__attribute__((amdgpu_waves_per_eu(8, 8)))   // 64-VGPR budget -> 8 waves/SIMD
void fused_disp_kernel(const float* __restrict__ left,
                       const float* __restrict__ right,
                       float* __restrict__ out) {
    __shared__ float4 red[2][16][32];  // [mat][channel-group(2ch)][w-quad]
    __shared__ float  Lh[WC];
    __shared__ float  Rhp[RSZ];
    __shared__ float  redL[2][WO];     // [dd-half][pixel]
    __shared__ float  redS[2][WO];

    // XCD-contiguous bijective swizzle: 512 blocks, 64 consecutive rows/XCD
    // -> per-XCD input working set ~0.6 MB (L2-resident, 4x row reuse on-XCD).
    int blk = blockIdx.x;
    int r   = (blk & 7) * (NBLK / 8) + (blk >> 3);
    int b   = r >> 8;
    int hh  = r & (HO - 1);

    float src_h = (float)hh * (63.0f / 255.0f);
    int h0 = (int)src_h; if (h0 > HC - 1) h0 = HC - 1;
    int h1 = h0 + 1;     if (h1 > HC - 1) h1 = HC - 1;
    float fh = src_h - (float)h0;

    int t = threadIdx.x;

    // ---- Phase 0: fused channel-sum (32 ch) + fh row blend, float4 loads ----
    // Same total loads per block as R3 (64 KB), spread over 1024 threads.
    {
        int mat = t >> 9;          // 0=left 1=right
        int uu  = t & 511;
        int cg  = uu >> 5;         // 16 groups of 2 channels
        int wq  = uu & 31;         // float4 quad in w
        const float* srcp = (mat ? right : left) + (size_t)b * (CC * HC * WC);
        float ax = 0.f, ay = 0.f, az = 0.f, aw = 0.f;
        float bx = 0.f, by = 0.f, bz = 0.f, bw = 0.f;
#pragma unroll
        for (int i = 0; i < 2; ++i) {
            int c = cg * 2 + i;
            float4 v0 = *(const float4*)(srcp + ((c * HC + h0) * WC + wq * 4));
            float4 v1 = *(const float4*)(srcp + ((c * HC + h1) * WC + wq * 4));
            ax += v0.x; ay += v0.y; az += v0.z; aw += v0.w;
            bx += v1.x; by += v1.y; bz += v1.z; bw += v1.w;
        }
        float gh = 1.f - fh;
        red[mat][cg][wq] = make_float4(fmaf(gh, ax, fh * bx), fmaf(gh, ay, fh * by),
                                       fmaf(gh, az, fh * bz), fmaf(gh, aw, fh * bw));
    }
    __syncthreads();
    // reduce the 16 channel-groups -> Lh[128] / Rhp[47..174]; zero the pads
    if (t < 256) {
        int mat = t >> 7;
        int w   = t & 127;
        const float* redf = (const float*)red;
        float s = 0.f;
#pragma unroll
        for (int cgi = 0; cgi < 16; ++cgi) s += redf[(mat * 16 + cgi) * 128 + w];
        if (mat == 0) Lh[w] = s;
        else          Rhp[RPAD + w] = s;
    } else {
        int z = t - 256;
        if (z < RPAD)       Rhp[z] = 0.f;        // leading zeros (R mask)
        else if (z == RPAD) Rhp[RSZ - 1] = 0.f;  // guard for w0==127, d==0
    }
    __syncthreads();

    // ---- Phase 2: 512 pixels x 2 dd-halves; 2 quarters per thread ----
    int p  = t & 511;                  // pixel (== output column)
    int k  = t >> 9;                   // dd half: 0 -> dd[0,95], 1 -> dd[96,191]
    int ww = p;

    float src_w = (float)ww * (127.0f / 511.0f);
    int w0 = (int)src_w; if (w0 > WC - 1) w0 = WC - 1;
    int w1 = w0 + 1;     if (w1 > WC - 1) w1 = WC - 1;
    float fw = src_w - (float)w0;

    const float L2E_SC = 1.4426950408889634f / 64.0f;  // log2(e) * (1/64 mean)
    float c0  = (1.f - fw) * L2E_SC;
    float c1  = fw * L2E_SC;
    float lw0 = Lh[w0], lw1 = Lh[w1];
    float cB0 = c0 * lw0, cB1 = c1 * lw1;
    float cA  = cB0 + cB1;
    float w0f = (float)w0;

    float ls0 = 0.f, ls1 = 0.f, ss0 = 0.f, ss1 = 0.f;
    // masked base needed only when w0 < 47 <=> p < 189; use p < 192 (wave-uniform).
    if (k == 0) {
        if (p < 192) { QUARTER(0, true)  QUARTER(1, true)  }
        else         { QUARTER(0, false) QUARTER(1, false) }
    } else {
        if (p < 192) { QUARTER(2, true)  QUARTER(3, true)  }
        else         { QUARTER(2, false) QUARTER(3, false) }
    }
    redL[k][p] = ls0 + ls1;
    redS[k][p] = ss0 + ss1;
    __syncthreads();

    // ---- Phase 3: combine dd-halves, soft-argmin, coalesced store ----
    if (t < WO) {
        float ls = redL[0][t] + redL[1][t];
        float ss = redS[0][t] + redS[1][t];
        out[(size_t)r * WO + t] = ss / ls;
    }
}

extern "C" void kernel_launch(void* const* d_in, const int* in_sizes, int n_in,
                              void* d_out, int out_size, void* d_ws, size_t ws_size,
                              hipStream_t stream) {
    const float* left  = (const float*)d_in[0];
    const float* right = (const float*)d_in[1];
    fused_disp_kernel<<<NBLK, 1024, 0, stream>>>(left, right, (float*)d_out);
}